// Round 9
// baseline (273.552 us; speedup 1.0000x reference)
//
#include <hip/hip_runtime.h>

#define D 128
#define KOUT 100
#define CHUNK 4096   // edges per pass-1 block

typedef __attribute__((ext_vector_type(8))) short short8;
typedef __attribute__((ext_vector_type(4))) float floatx4;

// ---------------- bf16 pack/unpack helpers ----------------
__device__ inline float bf_lo(unsigned int u) { return __uint_as_float(u << 16); }
__device__ inline float bf_hi(unsigned int u) { return __uint_as_float(u & 0xFFFF0000u); }

__device__ inline unsigned int bf_round(float a) {      // f32 -> bf16 bits (RNE)
    unsigned int ua = __float_as_uint(a);
    return (ua + 0x7FFFu + ((ua >> 16) & 1u)) >> 16;
}
__device__ inline unsigned int pack_bf(float a, float b) {
    return bf_round(a) | (bf_round(b) << 16);
}

// ---------------- MFMA GEMM body (shared) ----------------
// block 256 = 4 waves; tile 64 rows x 128 cols; wave w: rows w*16..+15.
// in_bf16: A-fragments read directly from packed-bf16 global rows.
// out_mode 1: packed-bf16 rows; row scaled by rsqrtf(deg[row]+1) if deg given.
// out_mode 2: +bias, softmax over first KOUT cols, f32 [nrows, KOUT] output.
__device__ void gemm_body(const void* __restrict__ Xin, const unsigned short* __restrict__ Wf,
                          const float* __restrict__ bias, const int* __restrict__ deg,
                          void* __restrict__ Y, int nrows, int in_bf16, int out_mode,
                          float* lds_f, int tile) {
    unsigned short* lds_h = (unsigned short*)lds_f;
    unsigned int* lds_u = (unsigned int*)lds_f;

    int tid = threadIdx.x;
    int w = tid >> 6, lane = tid & 63;
    int quad = lane >> 4, m16 = lane & 15;
    int r0 = tile * 64;

    if (!in_bf16) {
        int row = tid >> 2, cg_ = tid & 3;
        bool valid = (r0 + row) < nrows;
        const float4* Xr = (const float4*)Xin + (size_t)(r0 + row) * 32 + cg_ * 8;
#pragma unroll
        for (int j = 0; j < 8; j++) {
            float4 v = valid ? Xr[j] : make_float4(0.f, 0.f, 0.f, 0.f);
            int c = cg_ * 32 + j * 4;
            lds_u[row * 68 + (c >> 1)]     = pack_bf(v.x, v.y);
            lds_u[row * 68 + (c >> 1) + 1] = pack_bf(v.z, v.w);
        }
        __syncthreads();
    }

    floatx4 acc[8];
#pragma unroll
    for (int ct = 0; ct < 8; ct++) acc[ct] = (floatx4){0.f, 0.f, 0.f, 0.f};

    int arow = r0 + w * 16 + m16;
    if (arow > nrows - 1) arow = nrows - 1;
    const unsigned int* Xb = (const unsigned int*)Xin;

    const short8* Wf8 = (const short8*)Wf;
#pragma unroll
    for (int kt = 0; kt < 4; kt++) {
        short8 a;
        if (in_bf16) {
            a = *(const short8*)(Xb + (size_t)arow * 64 + kt * 16 + quad * 4);
        } else {
            a = *(const short8*)(lds_h + (w * 16 + m16) * 136 + kt * 32 + quad * 8);
        }
#pragma unroll
        for (int ct = 0; ct < 8; ct++) {
            short8 b = Wf8[(kt * 8 + ct) * 64 + lane];
            acc[ct] = __builtin_amdgcn_mfma_f32_16x16x32_bf16(a, b, acc[ct], 0, 0, 0);
        }
    }

    if (out_mode == 1) {
        __syncthreads();   // reuse LDS as f32 out staging [64][130]
#pragma unroll
        for (int ct = 0; ct < 8; ct++) {
#pragma unroll
            for (int r = 0; r < 4; r++) {
                int rl = w * 16 + quad * 4 + r;
                lds_f[rl * 130 + ct * 16 + m16] = acc[ct][r];
            }
        }
        __syncthreads();
        unsigned int* Yb = (unsigned int*)Y;
        for (int r = 0; r < 16; r++) {
            int row = r0 + w * 16 + r;
            if (row < nrows) {
                float sc = deg ? rsqrtf((float)(deg[row] + 1)) : 1.f;   // == dinv[row]
                float lo = lds_f[(w * 16 + r) * 130 + 2 * lane] * sc;
                float hi = lds_f[(w * 16 + r) * 130 + 2 * lane + 1] * sc;
                Yb[(size_t)row * 64 + lane] = pack_bf(lo, hi);
            }
        }
    } else {
        // out_mode 2: bias + softmax over cols < KOUT, f32 output [nrows, KOUT]
        float bb[8];
#pragma unroll
        for (int ct = 0; ct < 8; ct++) bb[ct] = bias[ct * 16 + m16];
        float* Yf = (float*)Y;
#pragma unroll
        for (int r = 0; r < 4; r++) {
            int row = r0 + w * 16 + quad * 4 + r;
            float vv[8];
            float mx = -1e30f;
#pragma unroll
            for (int ct = 0; ct < 8; ct++) {
                int col = ct * 16 + m16;
                vv[ct] = (col < KOUT) ? acc[ct][r] + bb[ct] : -1e30f;
                mx = fmaxf(mx, vv[ct]);
            }
#pragma unroll
            for (int off = 1; off < 16; off <<= 1) mx = fmaxf(mx, __shfl_xor(mx, off));
            float se = 0.f;
#pragma unroll
            for (int ct = 0; ct < 8; ct++) {
                vv[ct] = (vv[ct] > -1e29f) ? __expf(vv[ct] - mx) : 0.f;
                se += vv[ct];
            }
#pragma unroll
            for (int off = 1; off < 16; off <<= 1) se += __shfl_xor(se, off);
            float inv = 1.f / se;
            if (row < nrows) {
#pragma unroll
                for (int ct = 0; ct < 8; ct++) {
                    int col = ct * 16 + m16;
                    if (col < KOUT) Yf[(size_t)row * KOUT + col] = vv[ct] * inv;
                }
            }
        }
    }
}

// ---------------- K1: [pass1 | prep] merged (independent work) ----------------
// pass1: bucket radix partition. bucket = dst >> 8; record bits[23:0]=src,
// bits[31:24]=dst&255. ALSO counts in-degrees via fire-and-forget atomics in
// the bucket-sorted scatter loop (localized to b*256..+255 per run).
// prep: Wf1 fragments + fused W2@Wa fragments + fused bias + zero-rows + sentinel.
// (bcur and deg are zeroed by a hipMemsetAsync before this kernel.)

__launch_bounds__(256)
__global__ void k_p1_prep(const int* __restrict__ ei, int E, int nbuck, int cap,
                          int* __restrict__ bcur, unsigned int* __restrict__ bdata,
                          int* __restrict__ deg,
                          const float* __restrict__ W1, const float* __restrict__ W2,
                          const float* __restrict__ Wa, const float* __restrict__ ba,
                          const float* __restrict__ b2,
                          unsigned short* __restrict__ Wf1, unsigned short* __restrict__ WfF,
                          float* __restrict__ bpad, int* __restrict__ rowptr,
                          unsigned int* __restrict__ zrowA, unsigned int* __restrict__ zrowB,
                          int n, int nbP1) {
    __shared__ float lds_f[64 * 130];          // 33280 B (pass1 uses 25.6 KB of it)
    int tid = threadIdx.x;

    if ((int)blockIdx.x < nbP1) {
        // ---------------- pass1 ----------------
        int* hist = (int*)lds_f;
        int* sc   = hist + 256;
        int* pfx  = sc + 256;
        int* cur  = pfx + 256;
        int* gbase = cur + 256;
        unsigned int* lbuf = (unsigned int*)(gbase + 256);     // 16 KB
        unsigned char* bkt = (unsigned char*)(lbuf + CHUNK);   // 4 KB

        int base = blockIdx.x * CHUNK;
        int cnt = E - base; if (cnt > CHUNK) cnt = CHUNK;

        hist[tid] = 0;
        __syncthreads();

        int src[CHUNK / 256];
        int dst[CHUNK / 256];
#pragma unroll
        for (int q = 0; q < CHUNK / 256; q++) {
            int li = tid + q * 256;
            if (li < cnt) {
                src[q] = ei[base + li];
                dst[q] = ei[E + base + li];
                atomicAdd(&hist[dst[q] >> 8], 1);
            }
        }
        __syncthreads();

        int v = hist[tid];
        sc[tid] = v;
        __syncthreads();
        for (int off = 1; off < 256; off <<= 1) {
            int t = (tid >= off) ? sc[tid - off] : 0;
            __syncthreads();
            sc[tid] += t;
            __syncthreads();
        }
        int excl = sc[tid] - v;
        pfx[tid] = excl;
        cur[tid] = excl;
        gbase[tid] = 0;
        if (tid < nbuck && v > 0) gbase[tid] = atomicAdd(&bcur[tid], v);
        __syncthreads();

#pragma unroll
        for (int q = 0; q < CHUNK / 256; q++) {
            int li = tid + q * 256;
            if (li < cnt) {
                int b = dst[q] >> 8;
                int p = atomicAdd(&cur[b], 1);
                lbuf[p] = (unsigned int)src[q] | ((unsigned int)(dst[q] & 255) << 24);
                bkt[p] = (unsigned char)b;
            }
        }
        __syncthreads();

        for (int p = tid; p < cnt; p += 256) {
            int b = bkt[p];
            unsigned int rec = lbuf[p];
            bdata[(size_t)b * cap + gbase[b] + (p - pfx[b])] = rec;
            atomicAdd(deg + b * 256 + (int)(rec >> 24), 1);   // in-degree count
        }
    } else {
        // ---------------- prep ----------------
        int idx = ((int)blockIdx.x - nbP1) * 256 + tid;
        if (idx < 2 * 16384) {
            int m = idx >> 14;
            int e = idx & 16383;
            int j = e & 7, lane = (e >> 3) & 63, ct = (e >> 9) & 7, kt = e >> 12;
            int k = kt * 32 + (lane >> 4) * 8 + j;
            int col = ct * 16 + (lane & 15);
            if (m == 0) {
                Wf1[e] = (unsigned short)bf_round(W1[k * 128 + col]);
            } else {
                // Wfused[k][col] = sum_mm W2[k][mm] * Wa[mm][col]  (f32 accumulate)
                float s = 0.f;
                if (col < KOUT) {
                    const float* w2r = W2 + k * 128;
#pragma unroll 8
                    for (int mm = 0; mm < 128; mm++)
                        s = fmaf(w2r[mm], Wa[mm * KOUT + col], s);
                }
                WfF[e] = (unsigned short)bf_round(s);
            }
        }
        if (idx < 128) {
            float s = 0.f;
            if (idx < KOUT) {
                for (int mm = 0; mm < 128; mm++)
                    s = fmaf(b2[mm], Wa[mm * KOUT + idx], s);
                s += ba[idx];
            }
            bpad[idx] = s;
        }
        if (idx < 64) { zrowA[idx] = 0u; zrowB[idx] = 0u; }
        if (idx == 64) rowptr[n] = E;   // sentinel
    }
}

// ---------------- K2: [bucket_build | gemm1] merged (independent work) ----------------
// build: rowptr + csr scatter (one block per bucket; needs pass1 complete).
// gemm1: X @ W1 with rsqrtf(deg+1) prescale epilogue (needs prep + deg; NOT build).
// Concurrent: build's 196 bursty blocks hide behind gemm1's 782 compute blocks.

__launch_bounds__(256)
__global__ void k_build_gemm(const unsigned int* __restrict__ bdata, const int* __restrict__ bcur,
                             int cap, int* __restrict__ rowptr, int* __restrict__ csr,
                             int n, int nbuck,
                             const float* __restrict__ X, const unsigned short* __restrict__ Wf1,
                             const int* __restrict__ deg, unsigned int* __restrict__ HbA) {
    __shared__ float lds_f[64 * 130];
    int tid = threadIdx.x;

    if ((int)blockIdx.x < nbuck) {
        // ---------------- bucket_build ----------------
        int* cnts = (int*)lds_f;
        int* sc   = cnts + 256;
        int* cur  = sc + 256;
        int* pbb  = cur + 256;

        int b = blockIdx.x;
        if (tid == 0) pbb[0] = 0;
        cnts[tid] = 0;
        __syncthreads();

        int part = 0;
        for (int t = tid; t < b; t += 256) part += bcur[t];
#pragma unroll
        for (int off = 32; off > 0; off >>= 1) part += __shfl_down(part, off);
        if ((tid & 63) == 0 && part != 0) atomicAdd(&pbb[0], part);

        int cnt = bcur[b];
        const unsigned int* p = bdata + (size_t)b * cap;
        for (int e = tid; e < cnt; e += 256) atomicAdd(&cnts[p[e] >> 24], 1);
        __syncthreads();

        int v = cnts[tid];
        sc[tid] = v;
        __syncthreads();
        for (int off = 1; off < 256; off <<= 1) {
            int t = (tid >= off) ? sc[tid - off] : 0;
            __syncthreads();
            sc[tid] += t;
            __syncthreads();
        }
        int gstart = pbb[0] + (sc[tid] - v);
        int node = b * 256 + tid;
        if (node < n) rowptr[node] = gstart;
        cur[tid] = gstart;
        __syncthreads();

        for (int e = tid; e < cnt; e += 256) {
            unsigned int u = p[e];
            int pos = atomicAdd(&cur[u >> 24], 1);
            csr[pos] = (int)(u & 0xFFFFFFu);
        }
    } else {
        // ---------------- gemm1 (layer 1) ----------------
        gemm_body(X, Wf1, nullptr, deg, HbA, n, 0, 1, lds_f, (int)blockIdx.x - nbuck);
    }
}

// ---------------- final fused attention GEMM ----------------
__launch_bounds__(256)
__global__ void k_gemm_final(const void* __restrict__ Xin, const unsigned short* __restrict__ WfF,
                             const float* __restrict__ bpad, void* __restrict__ out, int n) {
    __shared__ float lds_f[64 * 130];
    gemm_body(Xin, WfF, bpad, nullptr, out, n, 1, 2, lds_f, (int)blockIdx.x);
}

// ---------------- Aggregate (r0-exact structure, proven 46.5 us) ----------------
// Ob[i] = bf16( post(di*(sum Hb'[src] + Hb'[i]) + b) ); rows dinv[src]-prescaled.
// one wave per node; 4 groups of 16 lanes, group = 1 edge, lane = uint4 (8 feats).
// di = rsqrtf(cnt+1) recomputed from rowptr diff (bit-identical to dinv; r6-validated).
// masked tail points at zero-row index n. sentinel rowptr[n]=E.
// post_scale: multiply final by di again (folds the eliminated GEMM2's prescale).

__launch_bounds__(256)
__global__ void aggregate_kernel(const uint4* __restrict__ Hb4, const int* __restrict__ csr,
                                 const int* __restrict__ rowptr,
                                 const float* __restrict__ bias,
                                 unsigned int* __restrict__ Ob, int n, int do_relu, int post_scale) {
    int wid = threadIdx.x >> 6, lane = threadIdx.x & 63;
    int g = lane >> 4, c = lane & 15;
    int i = blockIdx.x * 4 + wid;
    if (i >= n) return;

    int start = rowptr[i];
    int cnt = rowptr[i + 1] - start;
    const int* cp = csr + start;
    float di = rsqrtf((float)(cnt + 1));          // == dinv[i]

    float acc[8];
    {   // self term (group 0 only)
        uint4 sv = Hb4[(size_t)i * 16 + c];
        unsigned int su[4] = {sv.x, sv.y, sv.z, sv.w};
        if (g != 0) { su[0] = su[1] = su[2] = su[3] = 0u; }
#pragma unroll
        for (int t = 0; t < 4; t++) {
            acc[2 * t]     = bf_lo(su[t]);
            acc[2 * t + 1] = bf_hi(su[t]);
        }
    }

    int s[4];
#pragma unroll
    for (int u = 0; u < 4; u++) {
        int idx = u * 4 + g;
        s[u] = (idx < cnt) ? cp[idx] : n;          // n = zero row
    }
    for (int e = 0; e < cnt; e += 16) {
        uint4 v[4];
#pragma unroll
        for (int u = 0; u < 4; u++) v[u] = Hb4[(size_t)s[u] * 16 + c];
        int ns[4];
#pragma unroll
        for (int u = 0; u < 4; u++) {
            int idx = e + 16 + u * 4 + g;
            ns[u] = (idx < cnt) ? cp[idx] : n;
        }
#pragma unroll
        for (int u = 0; u < 4; u++) {
            unsigned int uu[4] = {v[u].x, v[u].y, v[u].z, v[u].w};
#pragma unroll
            for (int t = 0; t < 4; t++) {
                acc[2 * t]     += bf_lo(uu[t]);
                acc[2 * t + 1] += bf_hi(uu[t]);
            }
        }
#pragma unroll
        for (int u = 0; u < 4; u++) s[u] = ns[u];
    }

    // butterfly across the 4 groups (lane bits 4,5)
#pragma unroll
    for (int j = 0; j < 8; j++) {
        acc[j] += __shfl_xor(acc[j], 16);
        acc[j] += __shfl_xor(acc[j], 32);
    }

    // lane (g,c) writes feature pair p = c*4+g (feats 8c+2g, 8c+2g+1)
    float2 bb = bias ? ((const float2*)bias)[c * 4 + g] : make_float2(0.f, 0.f);
    float fx = acc[g * 2]     * di + bb.x;
    float fy = acc[g * 2 + 1] * di + bb.y;
    if (do_relu) { fx = fmaxf(fx, 0.f); fy = fmaxf(fy, 0.f); }
    if (post_scale) { fx *= di; fy *= di; }
    Ob[(size_t)i * 64 + c * 4 + g] = pack_bf(fx, fy);
}

// ---------------- launch ----------------

extern "C" void kernel_launch(void* const* d_in, const int* in_sizes, int n_in,
                              void* d_out, int out_size, void* d_ws, size_t ws_size,
                              hipStream_t stream) {
    const float* x  = (const float*)d_in[0];
    const int*   ei = (const int*)d_in[1];     // [2,E] int32
    const float* W1 = (const float*)d_in[2];
    const float* b1 = (const float*)d_in[3];
    const float* W2 = (const float*)d_in[4];
    const float* b2 = (const float*)d_in[5];
    const float* Wa = (const float*)d_in[6];
    const float* ba = (const float*)d_in[7];
    float* out = (float*)d_out;

    int N = in_sizes[0] / D;
    int E = in_sizes[1] / 2;

    int nbuck = (N + 255) >> 8;                       // 196 for N=50000
    int cap = ((E / nbuck) + 2048 + 63) & ~63;

    char* w = (char*)d_ws;
    size_t off = 0;
    auto carve = [&](size_t bytes) -> void* {
        void* p = w + off;
        off = (off + bytes + 255) & ~(size_t)255;
        return p;
    };
    int*   bcur   = (int*)carve(256 * 4);             // bcur + deg contiguous
    int*   deg    = (int*)carve((size_t)N * 4);       // (one memset covers both)
    int*   rowptr = (int*)carve((size_t)(N + 1) * 4);
    unsigned int* bdata = (unsigned int*)carve((size_t)nbuck * cap * 4);
    int*   csr    = (int*)carve((size_t)E * 4);
    unsigned short* Wf1 = (unsigned short*)carve(16384 * 2);
    unsigned short* WfF = (unsigned short*)carve(16384 * 2);
    float* bpad   = (float*)carve(512);
    unsigned int* HbA = (unsigned int*)carve((size_t)(N + 1) * 64 * 4);  // +1 zero row
    unsigned int* HbB = (unsigned int*)carve((size_t)(N + 1) * 64 * 4);
    (void)ws_size; (void)n_in; (void)out_size;

    int nbNode4 = (N + 3) / 4;
    int nbGemm = (N + 63) / 64;
    int nbP1 = (E + CHUNK - 1) / CHUNK;

    // zero bcur (1 KB) + deg (N*4), contiguous
    (void)hipMemsetAsync(bcur, 0, 1024 + (size_t)N * 4, stream);

    // K1: pass1 (+deg count)  ||  prep (Wf1, W2@Wa, bias, zero-rows, sentinel)
    k_p1_prep<<<nbP1 + 128, 256, 0, stream>>>(ei, E, nbuck, cap, bcur, bdata, deg,
                                              W1, W2, Wa, ba, b2, Wf1, WfF, bpad, rowptr,
                                              HbA + (size_t)N * 64, HbB + (size_t)N * 64,
                                              N, nbP1);
    // K2: build (rowptr+csr)  ||  gemm1 (X@W1, deg-prescale epilogue)
    k_build_gemm<<<nbuck + nbGemm, 256, 0, stream>>>(bdata, bcur, cap, rowptr, csr, N, nbuck,
                                                     x, Wf1, deg, HbA);
    // agg1: h1p_i = bf16( dinv_i * relu(acc*dinv_i + b1) )
    aggregate_kernel<<<nbNode4, 256, 0, stream>>>((const uint4*)HbA, csr, rowptr, b1, HbB, N, 1, 1);
    // agg2: G_i = bf16( dinv_i * acc )
    aggregate_kernel<<<nbNode4, 256, 0, stream>>>((const uint4*)HbB, csr, rowptr, nullptr, HbA, N, 0, 0);
    // fused attention: out = softmax( G @ (W2@Wa) + (b2@Wa + ba) )
    k_gemm_final<<<nbGemm, 256, 0, stream>>>(HbA, WfF, bpad, out, N);
}

// Round 10
// 241.725 us; speedup vs baseline: 1.1317x; 1.1317x over previous
//
#include <hip/hip_runtime.h>

#define D 128
#define KOUT 100
#define CHUNK 4096   // edges per pass-1 block

typedef __attribute__((ext_vector_type(8))) short short8;
typedef __attribute__((ext_vector_type(4))) float floatx4;

// ---------------- bf16 pack/unpack helpers ----------------
__device__ inline float bf_lo(unsigned int u) { return __uint_as_float(u << 16); }
__device__ inline float bf_hi(unsigned int u) { return __uint_as_float(u & 0xFFFF0000u); }

__device__ inline unsigned int bf_round(float a) {      // f32 -> bf16 bits (RNE)
    unsigned int ua = __float_as_uint(a);
    return (ua + 0x7FFFu + ((ua >> 16) & 1u)) >> 16;
}
__device__ inline unsigned int pack_bf(float a, float b) {
    return bf_round(a) | (bf_round(b) << 16);
}

// ---------------- MFMA GEMM body (shared) ----------------
// block 256 = 4 waves; tile 64 rows x 128 cols; wave w: rows w*16..+15.
// in_bf16: A-fragments read directly from packed-bf16 global rows.
// out_mode 1: packed-bf16 rows (no scaling -- dinv now applied inside aggregate).
// out_mode 2: +bias, softmax over first KOUT cols, f32 [nrows, KOUT] output.
__device__ void gemm_body(const void* __restrict__ Xin, const unsigned short* __restrict__ Wf,
                          const float* __restrict__ bias,
                          void* __restrict__ Y, int nrows, int in_bf16, int out_mode,
                          float* lds_f, int tile) {
    unsigned short* lds_h = (unsigned short*)lds_f;
    unsigned int* lds_u = (unsigned int*)lds_f;

    int tid = threadIdx.x;
    int w = tid >> 6, lane = tid & 63;
    int quad = lane >> 4, m16 = lane & 15;
    int r0 = tile * 64;

    if (!in_bf16) {
        int row = tid >> 2, cg_ = tid & 3;
        bool valid = (r0 + row) < nrows;
        const float4* Xr = (const float4*)Xin + (size_t)(r0 + row) * 32 + cg_ * 8;
#pragma unroll
        for (int j = 0; j < 8; j++) {
            float4 v = valid ? Xr[j] : make_float4(0.f, 0.f, 0.f, 0.f);
            int c = cg_ * 32 + j * 4;
            lds_u[row * 68 + (c >> 1)]     = pack_bf(v.x, v.y);
            lds_u[row * 68 + (c >> 1) + 1] = pack_bf(v.z, v.w);
        }
        __syncthreads();
    }

    floatx4 acc[8];
#pragma unroll
    for (int ct = 0; ct < 8; ct++) acc[ct] = (floatx4){0.f, 0.f, 0.f, 0.f};

    int arow = r0 + w * 16 + m16;
    if (arow > nrows - 1) arow = nrows - 1;
    const unsigned int* Xb = (const unsigned int*)Xin;

    const short8* Wf8 = (const short8*)Wf;
#pragma unroll
    for (int kt = 0; kt < 4; kt++) {
        short8 a;
        if (in_bf16) {
            a = *(const short8*)(Xb + (size_t)arow * 64 + kt * 16 + quad * 4);
        } else {
            a = *(const short8*)(lds_h + (w * 16 + m16) * 136 + kt * 32 + quad * 8);
        }
#pragma unroll
        for (int ct = 0; ct < 8; ct++) {
            short8 b = Wf8[(kt * 8 + ct) * 64 + lane];
            acc[ct] = __builtin_amdgcn_mfma_f32_16x16x32_bf16(a, b, acc[ct], 0, 0, 0);
        }
    }

    if (out_mode == 1) {
        __syncthreads();   // reuse LDS as f32 out staging [64][130]
#pragma unroll
        for (int ct = 0; ct < 8; ct++) {
#pragma unroll
            for (int r = 0; r < 4; r++) {
                int rl = w * 16 + quad * 4 + r;
                lds_f[rl * 130 + ct * 16 + m16] = acc[ct][r];
            }
        }
        __syncthreads();
        unsigned int* Yb = (unsigned int*)Y;
        for (int r = 0; r < 16; r++) {
            int row = r0 + w * 16 + r;
            if (row < nrows) {
                float lo = lds_f[(w * 16 + r) * 130 + 2 * lane];
                float hi = lds_f[(w * 16 + r) * 130 + 2 * lane + 1];
                Yb[(size_t)row * 64 + lane] = pack_bf(lo, hi);
            }
        }
    } else {
        // out_mode 2: bias + softmax over cols < KOUT, f32 output [nrows, KOUT]
        float bb[8];
#pragma unroll
        for (int ct = 0; ct < 8; ct++) bb[ct] = bias[ct * 16 + m16];
        float* Yf = (float*)Y;
#pragma unroll
        for (int r = 0; r < 4; r++) {
            int row = r0 + w * 16 + quad * 4 + r;
            float vv[8];
            float mx = -1e30f;
#pragma unroll
            for (int ct = 0; ct < 8; ct++) {
                int col = ct * 16 + m16;
                vv[ct] = (col < KOUT) ? acc[ct][r] + bb[ct] : -1e30f;
                mx = fmaxf(mx, vv[ct]);
            }
#pragma unroll
            for (int off = 1; off < 16; off <<= 1) mx = fmaxf(mx, __shfl_xor(mx, off));
            float se = 0.f;
#pragma unroll
            for (int ct = 0; ct < 8; ct++) {
                vv[ct] = (vv[ct] > -1e29f) ? __expf(vv[ct] - mx) : 0.f;
                se += vv[ct];
            }
#pragma unroll
            for (int off = 1; off < 16; off <<= 1) se += __shfl_xor(se, off);
            float inv = 1.f / se;
            if (row < nrows) {
#pragma unroll
                for (int ct = 0; ct < 8; ct++) {
                    int col = ct * 16 + m16;
                    if (col < KOUT) Yf[(size_t)row * KOUT + col] = vv[ct] * inv;
                }
            }
        }
    }
}

// ---------------- K1: [pass1 | prep] merged (independent work) ----------------
// pass1: bucket radix partition. bucket = dst >> 8; record bits[23:0]=src,
// bits[31:24]=dst&255. NO deg atomics (r9: 1.6M scattered L2 atomics serialized
// at ~128 collisions/line -> 40us stall. dinv comes from bucket_build as in r7).
// prep: Wf1 fragments + fused W2@Wa fragments + fused bias + zero-rows +
// rowptr sentinel + dinv[n]=0 sentinel. (bcur zeroed by hipMemsetAsync.)

__launch_bounds__(256)
__global__ void k_p1_prep(const int* __restrict__ ei, int E, int nbuck, int cap,
                          int* __restrict__ bcur, unsigned int* __restrict__ bdata,
                          const float* __restrict__ W1, const float* __restrict__ W2,
                          const float* __restrict__ Wa, const float* __restrict__ ba,
                          const float* __restrict__ b2,
                          unsigned short* __restrict__ Wf1, unsigned short* __restrict__ WfF,
                          float* __restrict__ bpad, int* __restrict__ rowptr,
                          float* __restrict__ dinv,
                          unsigned int* __restrict__ zrowA, unsigned int* __restrict__ zrowB,
                          int n, int nbP1) {
    __shared__ float lds_f[64 * 130];          // 33280 B (pass1 uses 25.6 KB of it)
    int tid = threadIdx.x;

    if ((int)blockIdx.x < nbP1) {
        // ---------------- pass1 ----------------
        int* hist = (int*)lds_f;
        int* sc   = hist + 256;
        int* pfx  = sc + 256;
        int* cur  = pfx + 256;
        int* gbase = cur + 256;
        unsigned int* lbuf = (unsigned int*)(gbase + 256);     // 16 KB
        unsigned char* bkt = (unsigned char*)(lbuf + CHUNK);   // 4 KB

        int base = blockIdx.x * CHUNK;
        int cnt = E - base; if (cnt > CHUNK) cnt = CHUNK;

        hist[tid] = 0;
        __syncthreads();

        int src[CHUNK / 256];
        int dst[CHUNK / 256];
#pragma unroll
        for (int q = 0; q < CHUNK / 256; q++) {
            int li = tid + q * 256;
            if (li < cnt) {
                src[q] = ei[base + li];
                dst[q] = ei[E + base + li];
                atomicAdd(&hist[dst[q] >> 8], 1);
            }
        }
        __syncthreads();

        int v = hist[tid];
        sc[tid] = v;
        __syncthreads();
        for (int off = 1; off < 256; off <<= 1) {
            int t = (tid >= off) ? sc[tid - off] : 0;
            __syncthreads();
            sc[tid] += t;
            __syncthreads();
        }
        int excl = sc[tid] - v;
        pfx[tid] = excl;
        cur[tid] = excl;
        gbase[tid] = 0;
        if (tid < nbuck && v > 0) gbase[tid] = atomicAdd(&bcur[tid], v);
        __syncthreads();

#pragma unroll
        for (int q = 0; q < CHUNK / 256; q++) {
            int li = tid + q * 256;
            if (li < cnt) {
                int b = dst[q] >> 8;
                int p = atomicAdd(&cur[b], 1);
                lbuf[p] = (unsigned int)src[q] | ((unsigned int)(dst[q] & 255) << 24);
                bkt[p] = (unsigned char)b;
            }
        }
        __syncthreads();

        for (int p = tid; p < cnt; p += 256) {
            int b = bkt[p];
            bdata[(size_t)b * cap + gbase[b] + (p - pfx[b])] = lbuf[p];
        }
    } else {
        // ---------------- prep ----------------
        int idx = ((int)blockIdx.x - nbP1) * 256 + tid;
        if (idx < 2 * 16384) {
            int m = idx >> 14;
            int e = idx & 16383;
            int j = e & 7, lane = (e >> 3) & 63, ct = (e >> 9) & 7, kt = e >> 12;
            int k = kt * 32 + (lane >> 4) * 8 + j;
            int col = ct * 16 + (lane & 15);
            if (m == 0) {
                Wf1[e] = (unsigned short)bf_round(W1[k * 128 + col]);
            } else {
                // Wfused[k][col] = sum_mm W2[k][mm] * Wa[mm][col]  (f32 accumulate)
                float s = 0.f;
                if (col < KOUT) {
                    const float* w2r = W2 + k * 128;
#pragma unroll 8
                    for (int mm = 0; mm < 128; mm++)
                        s = fmaf(w2r[mm], Wa[mm * KOUT + col], s);
                }
                WfF[e] = (unsigned short)bf_round(s);
            }
        }
        if (idx < 128) {
            float s = 0.f;
            if (idx < KOUT) {
                for (int mm = 0; mm < 128; mm++)
                    s = fmaf(b2[mm], Wa[mm * KOUT + idx], s);
                s += ba[idx];
            }
            bpad[idx] = s;
        }
        if (idx < 64) { zrowA[idx] = 0u; zrowB[idx] = 0u; }
        if (idx == 64) rowptr[n] = E;     // sentinel
        if (idx == 65) dinv[n] = 0.f;     // zero-row dinv sentinel (masked lanes)
    }
}

// ---------------- K2: [bucket_build | gemm1] merged (independent work) ----------------
// build: dinv + rowptr + csr scatter (needs pass1). gemm1: H1 = bf16(X@W1),
// UNSCALED (dinv moved into aggregate's gather) -> needs only prep, NOT build.
// Concurrent: build's 196 bursty blocks hide behind gemm1's 782 compute blocks.

__launch_bounds__(256)
__global__ void k_build_gemm(const unsigned int* __restrict__ bdata, const int* __restrict__ bcur,
                             int cap, float* __restrict__ dinv,
                             int* __restrict__ rowptr, int* __restrict__ csr,
                             int n, int nbuck,
                             const float* __restrict__ X, const unsigned short* __restrict__ Wf1,
                             unsigned int* __restrict__ HbA) {
    __shared__ float lds_f[64 * 130];
    int tid = threadIdx.x;

    if ((int)blockIdx.x < nbuck) {
        // ---------------- bucket_build ----------------
        int* cnts = (int*)lds_f;
        int* sc   = cnts + 256;
        int* cur  = sc + 256;
        int* pbb  = cur + 256;

        int b = blockIdx.x;
        if (tid == 0) pbb[0] = 0;
        cnts[tid] = 0;
        __syncthreads();

        int part = 0;
        for (int t = tid; t < b; t += 256) part += bcur[t];
#pragma unroll
        for (int off = 32; off > 0; off >>= 1) part += __shfl_down(part, off);
        if ((tid & 63) == 0 && part != 0) atomicAdd(&pbb[0], part);

        int cnt = bcur[b];
        const unsigned int* p = bdata + (size_t)b * cap;
        for (int e = tid; e < cnt; e += 256) atomicAdd(&cnts[p[e] >> 24], 1);
        __syncthreads();

        int v = cnts[tid];
        sc[tid] = v;
        __syncthreads();
        for (int off = 1; off < 256; off <<= 1) {
            int t = (tid >= off) ? sc[tid - off] : 0;
            __syncthreads();
            sc[tid] += t;
            __syncthreads();
        }
        int gstart = pbb[0] + (sc[tid] - v);
        int node = b * 256 + tid;
        if (node < n) {
            dinv[node] = rsqrtf((float)(v + 1));
            rowptr[node] = gstart;
        }
        cur[tid] = gstart;
        __syncthreads();

        for (int e = tid; e < cnt; e += 256) {
            unsigned int u = p[e];
            int pos = atomicAdd(&cur[u >> 24], 1);
            csr[pos] = (int)(u & 0xFFFFFFu);
        }
    } else {
        // ---------------- gemm1 (layer 1, unscaled output) ----------------
        gemm_body(X, Wf1, nullptr, HbA, n, 0, 1, lds_f, (int)blockIdx.x - nbuck);
    }
}

// ---------------- final fused attention GEMM ----------------
__launch_bounds__(256)
__global__ void k_gemm_final(const void* __restrict__ Xin, const unsigned short* __restrict__ WfF,
                             const float* __restrict__ bpad, void* __restrict__ out, int n) {
    __shared__ float lds_f[64 * 130];
    gemm_body(Xin, WfF, bpad, out, n, 1, 2, lds_f, (int)blockIdx.x);
}

// ---------------- Aggregate (r0 structure + in-gather dinv scaling) ----------------
// Ob[i] = bf16( relu?( di*(sum_s dinv[s]*H[s] + di*H[i]) + b ) ), H rows UNSCALED.
// one wave per node; 4 groups of 16 lanes, group = 1 edge, lane = uint4 (8 feats).
// dinv[s[u]] is wave-group-uniform (16 lanes same addr -> broadcast 4B load,
// 4 per 16 edges); accumulate via v_fmac (same VALU cost as v_add).
// di = rsqrtf(cnt+1) (bit-identical to dinv[i]; r6-validated).
// masked tail -> zero row n with dinv[n]=0 sentinel. rowptr[n]=E sentinel.

__launch_bounds__(256)
__global__ void aggregate_kernel(const uint4* __restrict__ Hb4, const int* __restrict__ csr,
                                 const int* __restrict__ rowptr, const float* __restrict__ dinv,
                                 const float* __restrict__ bias,
                                 unsigned int* __restrict__ Ob, int n, int do_relu) {
    int wid = threadIdx.x >> 6, lane = threadIdx.x & 63;
    int g = lane >> 4, c = lane & 15;
    int i = blockIdx.x * 4 + wid;
    if (i >= n) return;

    int start = rowptr[i];
    int cnt = rowptr[i + 1] - start;
    const int* cp = csr + start;
    float di = rsqrtf((float)(cnt + 1));          // == dinv[i]

    float acc[8];
    {   // self term: di * H[i] (group 0 only)
        uint4 sv = Hb4[(size_t)i * 16 + c];
        unsigned int su[4] = {sv.x, sv.y, sv.z, sv.w};
        if (g != 0) { su[0] = su[1] = su[2] = su[3] = 0u; }
#pragma unroll
        for (int t = 0; t < 4; t++) {
            acc[2 * t]     = di * bf_lo(su[t]);
            acc[2 * t + 1] = di * bf_hi(su[t]);
        }
    }

    int s[4];
    float dv[4];
#pragma unroll
    for (int u = 0; u < 4; u++) {
        int idx = u * 4 + g;
        s[u] = (idx < cnt) ? cp[idx] : n;          // n = zero row
    }
#pragma unroll
    for (int u = 0; u < 4; u++) dv[u] = dinv[s[u]];

    for (int e = 0; e < cnt; e += 16) {
        uint4 v[4];
#pragma unroll
        for (int u = 0; u < 4; u++) v[u] = Hb4[(size_t)s[u] * 16 + c];
        int ns[4];
#pragma unroll
        for (int u = 0; u < 4; u++) {
            int idx = e + 16 + u * 4 + g;
            ns[u] = (idx < cnt) ? cp[idx] : n;
        }
        float ndv[4];
#pragma unroll
        for (int u = 0; u < 4; u++) ndv[u] = dinv[ns[u]];
#pragma unroll
        for (int u = 0; u < 4; u++) {
            unsigned int uu[4] = {v[u].x, v[u].y, v[u].z, v[u].w};
#pragma unroll
            for (int t = 0; t < 4; t++) {
                acc[2 * t]     = fmaf(dv[u], bf_lo(uu[t]), acc[2 * t]);
                acc[2 * t + 1] = fmaf(dv[u], bf_hi(uu[t]), acc[2 * t + 1]);
            }
        }
#pragma unroll
        for (int u = 0; u < 4; u++) { s[u] = ns[u]; dv[u] = ndv[u]; }
    }

    // butterfly across the 4 groups (lane bits 4,5)
#pragma unroll
    for (int j = 0; j < 8; j++) {
        acc[j] += __shfl_xor(acc[j], 16);
        acc[j] += __shfl_xor(acc[j], 32);
    }

    // lane (g,c) writes feature pair p = c*4+g (feats 8c+2g, 8c+2g+1)
    float2 bb = bias ? ((const float2*)bias)[c * 4 + g] : make_float2(0.f, 0.f);
    float fx = acc[g * 2]     * di + bb.x;
    float fy = acc[g * 2 + 1] * di + bb.y;
    if (do_relu) { fx = fmaxf(fx, 0.f); fy = fmaxf(fy, 0.f); }
    Ob[(size_t)i * 64 + c * 4 + g] = pack_bf(fx, fy);
}

// ---------------- launch ----------------

extern "C" void kernel_launch(void* const* d_in, const int* in_sizes, int n_in,
                              void* d_out, int out_size, void* d_ws, size_t ws_size,
                              hipStream_t stream) {
    const float* x  = (const float*)d_in[0];
    const int*   ei = (const int*)d_in[1];     // [2,E] int32
    const float* W1 = (const float*)d_in[2];
    const float* b1 = (const float*)d_in[3];
    const float* W2 = (const float*)d_in[4];
    const float* b2 = (const float*)d_in[5];
    const float* Wa = (const float*)d_in[6];
    const float* ba = (const float*)d_in[7];
    float* out = (float*)d_out;

    int N = in_sizes[0] / D;
    int E = in_sizes[1] / 2;

    int nbuck = (N + 255) >> 8;                       // 196 for N=50000
    int cap = ((E / nbuck) + 2048 + 63) & ~63;

    char* w = (char*)d_ws;
    size_t off = 0;
    auto carve = [&](size_t bytes) -> void* {
        void* p = w + off;
        off = (off + bytes + 255) & ~(size_t)255;
        return p;
    };
    int*   bcur   = (int*)carve(256 * 4);
    float* dinv   = (float*)carve((size_t)(N + 1) * 4);   // +1: dinv[N]=0 sentinel
    int*   rowptr = (int*)carve((size_t)(N + 1) * 4);
    unsigned int* bdata = (unsigned int*)carve((size_t)nbuck * cap * 4);
    int*   csr    = (int*)carve((size_t)E * 4);
    unsigned short* Wf1 = (unsigned short*)carve(16384 * 2);
    unsigned short* WfF = (unsigned short*)carve(16384 * 2);
    float* bpad   = (float*)carve(512);
    unsigned int* HbA = (unsigned int*)carve((size_t)(N + 1) * 64 * 4);  // +1 zero row
    unsigned int* HbB = (unsigned int*)carve((size_t)(N + 1) * 64 * 4);
    (void)ws_size; (void)n_in; (void)out_size;

    int nbNode4 = (N + 3) / 4;
    int nbGemm = (N + 63) / 64;
    int nbP1 = (E + CHUNK - 1) / CHUNK;

    // zero bcur only (deg scheme removed)
    (void)hipMemsetAsync(bcur, 0, 256 * 4, stream);

    // K1: pass1  ||  prep (Wf1, W2@Wa, fused bias, zero-rows, sentinels)
    k_p1_prep<<<nbP1 + 128, 256, 0, stream>>>(ei, E, nbuck, cap, bcur, bdata,
                                              W1, W2, Wa, ba, b2, Wf1, WfF, bpad,
                                              rowptr, dinv,
                                              HbA + (size_t)N * 64, HbB + (size_t)N * 64,
                                              N, nbP1);
    // K2: build (dinv+rowptr+csr)  ||  gemm1 (H1 = bf16(X@W1), unscaled)
    k_build_gemm<<<nbuck + nbGemm, 256, 0, stream>>>(bdata, bcur, cap, dinv, rowptr, csr,
                                                     N, nbuck, x, Wf1, HbA);
    // agg1: h1_i = bf16( relu( di*(sum dinv_s*H1_s + di*H1_i) + b1 ) )
    aggregate_kernel<<<nbNode4, 256, 0, stream>>>((const uint4*)HbA, csr, rowptr, dinv, b1, HbB, N, 1);
    // agg2: G_i = bf16( di*(sum dinv_s*h1_s + di*h1_i) )
    aggregate_kernel<<<nbNode4, 256, 0, stream>>>((const uint4*)HbB, csr, rowptr, dinv, nullptr, HbA, N, 0);
    // fused attention: out = softmax( G @ (W2@Wa) + (b2@Wa + ba) )
    k_gemm_final<<<nbGemm, 256, 0, stream>>>(HbA, WfF, bpad, out, N);
}

// Round 11
// 237.354 us; speedup vs baseline: 1.1525x; 1.0184x over previous
//
#include <hip/hip_runtime.h>

#define D 128
#define KOUT 100
#define CHUNK 4096   // edges per pass-1 block

typedef __attribute__((ext_vector_type(8))) short short8;
typedef __attribute__((ext_vector_type(4))) float floatx4;

// ---------------- bf16 pack/unpack helpers ----------------
__device__ inline float bf_lo(unsigned int u) { return __uint_as_float(u << 16); }
__device__ inline float bf_hi(unsigned int u) { return __uint_as_float(u & 0xFFFF0000u); }

__device__ inline unsigned int bf_round(float a) {      // f32 -> bf16 bits (RNE)
    unsigned int ua = __float_as_uint(a);
    return (ua + 0x7FFFu + ((ua >> 16) & 1u)) >> 16;
}
__device__ inline unsigned int pack_bf(float a, float b) {
    return bf_round(a) | (bf_round(b) << 16);
}

// ---------------- MFMA GEMM body (shared) ----------------
// block 256 = 4 waves; tile 64 rows x 128 cols; wave w: rows w*16..+15.
// in_bf16: A-fragments read directly from packed-bf16 global rows.
// out_mode 1: packed-bf16 rows (unscaled; dinv handled in aggregates).
// out_mode 2: +bias, softmax over first KOUT cols, f32 [nrows, KOUT] output.
__device__ void gemm_body(const void* __restrict__ Xin, const unsigned short* __restrict__ Wf,
                          const float* __restrict__ bias,
                          void* __restrict__ Y, int nrows, int in_bf16, int out_mode,
                          float* lds_f, int tile) {
    unsigned short* lds_h = (unsigned short*)lds_f;
    unsigned int* lds_u = (unsigned int*)lds_f;

    int tid = threadIdx.x;
    int w = tid >> 6, lane = tid & 63;
    int quad = lane >> 4, m16 = lane & 15;
    int r0 = tile * 64;

    if (!in_bf16) {
        int row = tid >> 2, cg_ = tid & 3;
        bool valid = (r0 + row) < nrows;
        const float4* Xr = (const float4*)Xin + (size_t)(r0 + row) * 32 + cg_ * 8;
#pragma unroll
        for (int j = 0; j < 8; j++) {
            float4 v = valid ? Xr[j] : make_float4(0.f, 0.f, 0.f, 0.f);
            int c = cg_ * 32 + j * 4;
            lds_u[row * 68 + (c >> 1)]     = pack_bf(v.x, v.y);
            lds_u[row * 68 + (c >> 1) + 1] = pack_bf(v.z, v.w);
        }
        __syncthreads();
    }

    floatx4 acc[8];
#pragma unroll
    for (int ct = 0; ct < 8; ct++) acc[ct] = (floatx4){0.f, 0.f, 0.f, 0.f};

    int arow = r0 + w * 16 + m16;
    if (arow > nrows - 1) arow = nrows - 1;
    const unsigned int* Xb = (const unsigned int*)Xin;

    const short8* Wf8 = (const short8*)Wf;
#pragma unroll
    for (int kt = 0; kt < 4; kt++) {
        short8 a;
        if (in_bf16) {
            a = *(const short8*)(Xb + (size_t)arow * 64 + kt * 16 + quad * 4);
        } else {
            a = *(const short8*)(lds_h + (w * 16 + m16) * 136 + kt * 32 + quad * 8);
        }
#pragma unroll
        for (int ct = 0; ct < 8; ct++) {
            short8 b = Wf8[(kt * 8 + ct) * 64 + lane];
            acc[ct] = __builtin_amdgcn_mfma_f32_16x16x32_bf16(a, b, acc[ct], 0, 0, 0);
        }
    }

    if (out_mode == 1) {
        __syncthreads();   // reuse LDS as f32 out staging [64][130]
#pragma unroll
        for (int ct = 0; ct < 8; ct++) {
#pragma unroll
            for (int r = 0; r < 4; r++) {
                int rl = w * 16 + quad * 4 + r;
                lds_f[rl * 130 + ct * 16 + m16] = acc[ct][r];
            }
        }
        __syncthreads();
        unsigned int* Yb = (unsigned int*)Y;
        for (int r = 0; r < 16; r++) {
            int row = r0 + w * 16 + r;
            if (row < nrows) {
                float lo = lds_f[(w * 16 + r) * 130 + 2 * lane];
                float hi = lds_f[(w * 16 + r) * 130 + 2 * lane + 1];
                Yb[(size_t)row * 64 + lane] = pack_bf(lo, hi);
            }
        }
    } else {
        // out_mode 2: bias + softmax over cols < KOUT, f32 output [nrows, KOUT]
        float bb[8];
#pragma unroll
        for (int ct = 0; ct < 8; ct++) bb[ct] = bias[ct * 16 + m16];
        float* Yf = (float*)Y;
#pragma unroll
        for (int r = 0; r < 4; r++) {
            int row = r0 + w * 16 + quad * 4 + r;
            float vv[8];
            float mx = -1e30f;
#pragma unroll
            for (int ct = 0; ct < 8; ct++) {
                int col = ct * 16 + m16;
                vv[ct] = (col < KOUT) ? acc[ct][r] + bb[ct] : -1e30f;
                mx = fmaxf(mx, vv[ct]);
            }
#pragma unroll
            for (int off = 1; off < 16; off <<= 1) mx = fmaxf(mx, __shfl_xor(mx, off));
            float se = 0.f;
#pragma unroll
            for (int ct = 0; ct < 8; ct++) {
                vv[ct] = (vv[ct] > -1e29f) ? __expf(vv[ct] - mx) : 0.f;
                se += vv[ct];
            }
#pragma unroll
            for (int off = 1; off < 16; off <<= 1) se += __shfl_xor(se, off);
            float inv = 1.f / se;
            if (row < nrows) {
#pragma unroll
                for (int ct = 0; ct < 8; ct++) {
                    int col = ct * 16 + m16;
                    if (col < KOUT) Yf[(size_t)row * KOUT + col] = vv[ct] * inv;
                }
            }
        }
    }
}

// ---------------- K1: [pass1 | prep] merged (independent work) ----------------
// pass1: bucket radix partition. bucket = dst >> 8; record bits[23:0]=src,
// bits[31:24]=dst&255. NO deg atomics (r9: scattered L2 atomics serialize).
// prep: Wf1 fragments + fused W2@Wa fragments + fused bias + zero-rows +
// rowptr sentinel + dinv[n]=0 sentinel. (bcur zeroed by hipMemsetAsync.)

__launch_bounds__(256)
__global__ void k_p1_prep(const int* __restrict__ ei, int E, int nbuck, int cap,
                          int* __restrict__ bcur, unsigned int* __restrict__ bdata,
                          const float* __restrict__ W1, const float* __restrict__ W2,
                          const float* __restrict__ Wa, const float* __restrict__ ba,
                          const float* __restrict__ b2,
                          unsigned short* __restrict__ Wf1, unsigned short* __restrict__ WfF,
                          float* __restrict__ bpad, int* __restrict__ rowptr,
                          float* __restrict__ dinv,
                          unsigned int* __restrict__ zrowA, unsigned int* __restrict__ zrowB,
                          int n, int nbP1) {
    __shared__ float lds_f[64 * 130];          // 33280 B (pass1 uses 25.6 KB of it)
    int tid = threadIdx.x;

    if ((int)blockIdx.x < nbP1) {
        // ---------------- pass1 ----------------
        int* hist = (int*)lds_f;
        int* sc   = hist + 256;
        int* pfx  = sc + 256;
        int* cur  = pfx + 256;
        int* gbase = cur + 256;
        unsigned int* lbuf = (unsigned int*)(gbase + 256);     // 16 KB
        unsigned char* bkt = (unsigned char*)(lbuf + CHUNK);   // 4 KB

        int base = blockIdx.x * CHUNK;
        int cnt = E - base; if (cnt > CHUNK) cnt = CHUNK;

        hist[tid] = 0;
        __syncthreads();

        int src[CHUNK / 256];
        int dst[CHUNK / 256];
#pragma unroll
        for (int q = 0; q < CHUNK / 256; q++) {
            int li = tid + q * 256;
            if (li < cnt) {
                src[q] = ei[base + li];
                dst[q] = ei[E + base + li];
                atomicAdd(&hist[dst[q] >> 8], 1);
            }
        }
        __syncthreads();

        int v = hist[tid];
        sc[tid] = v;
        __syncthreads();
        for (int off = 1; off < 256; off <<= 1) {
            int t = (tid >= off) ? sc[tid - off] : 0;
            __syncthreads();
            sc[tid] += t;
            __syncthreads();
        }
        int excl = sc[tid] - v;
        pfx[tid] = excl;
        cur[tid] = excl;
        gbase[tid] = 0;
        if (tid < nbuck && v > 0) gbase[tid] = atomicAdd(&bcur[tid], v);
        __syncthreads();

#pragma unroll
        for (int q = 0; q < CHUNK / 256; q++) {
            int li = tid + q * 256;
            if (li < cnt) {
                int b = dst[q] >> 8;
                int p = atomicAdd(&cur[b], 1);
                lbuf[p] = (unsigned int)src[q] | ((unsigned int)(dst[q] & 255) << 24);
                bkt[p] = (unsigned char)b;
            }
        }
        __syncthreads();

        for (int p = tid; p < cnt; p += 256) {
            int b = bkt[p];
            bdata[(size_t)b * cap + gbase[b] + (p - pfx[b])] = lbuf[p];
        }
    } else {
        // ---------------- prep ----------------
        int idx = ((int)blockIdx.x - nbP1) * 256 + tid;
        if (idx < 2 * 16384) {
            int m = idx >> 14;
            int e = idx & 16383;
            int j = e & 7, lane = (e >> 3) & 63, ct = (e >> 9) & 7, kt = e >> 12;
            int k = kt * 32 + (lane >> 4) * 8 + j;
            int col = ct * 16 + (lane & 15);
            if (m == 0) {
                Wf1[e] = (unsigned short)bf_round(W1[k * 128 + col]);
            } else {
                // Wfused[k][col] = sum_mm W2[k][mm] * Wa[mm][col]  (f32 accumulate)
                float s = 0.f;
                if (col < KOUT) {
                    const float* w2r = W2 + k * 128;
#pragma unroll 8
                    for (int mm = 0; mm < 128; mm++)
                        s = fmaf(w2r[mm], Wa[mm * KOUT + col], s);
                }
                WfF[e] = (unsigned short)bf_round(s);
            }
        }
        if (idx < 128) {
            float s = 0.f;
            if (idx < KOUT) {
                for (int mm = 0; mm < 128; mm++)
                    s = fmaf(b2[mm], Wa[mm * KOUT + idx], s);
                s += ba[idx];
            }
            bpad[idx] = s;
        }
        if (idx < 64) { zrowA[idx] = 0u; zrowB[idx] = 0u; }
        if (idx == 64) rowptr[n] = E;     // sentinel
        if (idx == 65) dinv[n] = 0.f;     // zero-row dinv sentinel (masked lanes)
    }
}

// ---------------- K2: [bucket_build | gemm1] merged (independent work) ----------------
// build: dinv + rowptr + csr scatter (needs pass1). gemm1: H1 = bf16(X@W1),
// UNSCALED (dinv applied in agg1's gather) -> needs only prep, NOT build.
// Concurrent: build's 196 bursty blocks hide behind gemm1's 782 compute blocks.

__launch_bounds__(256)
__global__ void k_build_gemm(const unsigned int* __restrict__ bdata, const int* __restrict__ bcur,
                             int cap, float* __restrict__ dinv,
                             int* __restrict__ rowptr, int* __restrict__ csr,
                             int n, int nbuck,
                             const float* __restrict__ X, const unsigned short* __restrict__ Wf1,
                             unsigned int* __restrict__ HbA) {
    __shared__ float lds_f[64 * 130];
    int tid = threadIdx.x;

    if ((int)blockIdx.x < nbuck) {
        // ---------------- bucket_build ----------------
        int* cnts = (int*)lds_f;
        int* sc   = cnts + 256;
        int* cur  = sc + 256;
        int* pbb  = cur + 256;

        int b = blockIdx.x;
        if (tid == 0) pbb[0] = 0;
        cnts[tid] = 0;
        __syncthreads();

        int part = 0;
        for (int t = tid; t < b; t += 256) part += bcur[t];
#pragma unroll
        for (int off = 32; off > 0; off >>= 1) part += __shfl_down(part, off);
        if ((tid & 63) == 0 && part != 0) atomicAdd(&pbb[0], part);

        int cnt = bcur[b];
        const unsigned int* p = bdata + (size_t)b * cap;
        for (int e = tid; e < cnt; e += 256) atomicAdd(&cnts[p[e] >> 24], 1);
        __syncthreads();

        int v = cnts[tid];
        sc[tid] = v;
        __syncthreads();
        for (int off = 1; off < 256; off <<= 1) {
            int t = (tid >= off) ? sc[tid - off] : 0;
            __syncthreads();
            sc[tid] += t;
            __syncthreads();
        }
        int gstart = pbb[0] + (sc[tid] - v);
        int node = b * 256 + tid;
        if (node < n) {
            dinv[node] = rsqrtf((float)(v + 1));
            rowptr[node] = gstart;
        }
        cur[tid] = gstart;
        __syncthreads();

        for (int e = tid; e < cnt; e += 256) {
            unsigned int u = p[e];
            int pos = atomicAdd(&cur[u >> 24], 1);
            csr[pos] = (int)(u & 0xFFFFFFu);
        }
    } else {
        // ---------------- gemm1 (layer 1, unscaled output) ----------------
        gemm_body(X, Wf1, nullptr, HbA, n, 0, 1, lds_f, (int)blockIdx.x - nbuck);
    }
}

// ---------------- final fused attention GEMM ----------------
__launch_bounds__(256)
__global__ void k_gemm_final(const void* __restrict__ Xin, const unsigned short* __restrict__ WfF,
                             const float* __restrict__ bpad, void* __restrict__ out, int n) {
    __shared__ float lds_f[64 * 130];
    gemm_body(Xin, WfF, bpad, out, n, 1, 2, lds_f, (int)blockIdx.x);
}

// ---------------- agg1: gather-dinv aggregate, prescaled output ----------------
// Input H rows UNSCALED. acc = sum_s dinv[s]*H[s] + di*H[i].
// Output: bf16( dinv_i * relu( acc*di + b1 ) )  -- prescaled for agg2 (r7 trick).
// dinv[s[u]] is group-uniform (16 lanes same addr -> broadcast 4B load).
// masked tail -> zero row n with dinv[n]=0 sentinel. rowptr[n]=E sentinel.

__launch_bounds__(256)
__global__ void agg_gather_kernel(const uint4* __restrict__ Hb4, const int* __restrict__ csr,
                                  const int* __restrict__ rowptr, const float* __restrict__ dinv,
                                  const float* __restrict__ bias,
                                  unsigned int* __restrict__ Ob, int n) {
    int wid = threadIdx.x >> 6, lane = threadIdx.x & 63;
    int g = lane >> 4, c = lane & 15;
    int i = blockIdx.x * 4 + wid;
    if (i >= n) return;

    int start = rowptr[i];
    int cnt = rowptr[i + 1] - start;
    const int* cp = csr + start;
    float di = rsqrtf((float)(cnt + 1));          // == dinv[i]

    float acc[8];
    {   // self term: di * H[i] (group 0 only)
        uint4 sv = Hb4[(size_t)i * 16 + c];
        unsigned int su[4] = {sv.x, sv.y, sv.z, sv.w};
        if (g != 0) { su[0] = su[1] = su[2] = su[3] = 0u; }
#pragma unroll
        for (int t = 0; t < 4; t++) {
            acc[2 * t]     = di * bf_lo(su[t]);
            acc[2 * t + 1] = di * bf_hi(su[t]);
        }
    }

    int s[4];
    float dv[4];
#pragma unroll
    for (int u = 0; u < 4; u++) {
        int idx = u * 4 + g;
        s[u] = (idx < cnt) ? cp[idx] : n;          // n = zero row
    }
#pragma unroll
    for (int u = 0; u < 4; u++) dv[u] = dinv[s[u]];

    for (int e = 0; e < cnt; e += 16) {
        uint4 v[4];
#pragma unroll
        for (int u = 0; u < 4; u++) v[u] = Hb4[(size_t)s[u] * 16 + c];
        int ns[4];
#pragma unroll
        for (int u = 0; u < 4; u++) {
            int idx = e + 16 + u * 4 + g;
            ns[u] = (idx < cnt) ? cp[idx] : n;
        }
        float ndv[4];
#pragma unroll
        for (int u = 0; u < 4; u++) ndv[u] = dinv[ns[u]];
#pragma unroll
        for (int u = 0; u < 4; u++) {
            unsigned int uu[4] = {v[u].x, v[u].y, v[u].z, v[u].w};
#pragma unroll
            for (int t = 0; t < 4; t++) {
                acc[2 * t]     = fmaf(dv[u], bf_lo(uu[t]), acc[2 * t]);
                acc[2 * t + 1] = fmaf(dv[u], bf_hi(uu[t]), acc[2 * t + 1]);
            }
        }
#pragma unroll
        for (int u = 0; u < 4; u++) { s[u] = ns[u]; dv[u] = ndv[u]; }
    }

    // butterfly across the 4 groups (lane bits 4,5)
#pragma unroll
    for (int j = 0; j < 8; j++) {
        acc[j] += __shfl_xor(acc[j], 16);
        acc[j] += __shfl_xor(acc[j], 32);
    }

    // lane (g,c) writes feature pair p = c*4+g (feats 8c+2g, 8c+2g+1)
    float2 bb = ((const float2*)bias)[c * 4 + g];
    float fx = acc[g * 2]     * di + bb.x;
    float fy = acc[g * 2 + 1] * di + bb.y;
    fx = fmaxf(fx, 0.f); fy = fmaxf(fy, 0.f);
    fx *= di; fy *= di;                           // prescale for agg2
    Ob[(size_t)i * 64 + c * 4 + g] = pack_bf(fx, fy);
}

// ---------------- agg2: prescaled-input aggregate (r0/r7-exact, 46.5 us) --------
// Input rows PRESCALED (h1' = dinv*h1). acc = sum_s h1'[s] + h1'[i];
// output G_i = bf16( acc * di )  (self-loop norm di^2 preserved). No bias/relu.

__launch_bounds__(256)
__global__ void agg_pre_kernel(const uint4* __restrict__ Hb4, const int* __restrict__ csr,
                               const int* __restrict__ rowptr,
                               unsigned int* __restrict__ Ob, int n) {
    int wid = threadIdx.x >> 6, lane = threadIdx.x & 63;
    int g = lane >> 4, c = lane & 15;
    int i = blockIdx.x * 4 + wid;
    if (i >= n) return;

    int start = rowptr[i];
    int cnt = rowptr[i + 1] - start;
    const int* cp = csr + start;
    float di = rsqrtf((float)(cnt + 1));          // == dinv[i]

    float acc[8];
    {   // self term (group 0 only); rows already dinv-prescaled
        uint4 sv = Hb4[(size_t)i * 16 + c];
        unsigned int su[4] = {sv.x, sv.y, sv.z, sv.w};
        if (g != 0) { su[0] = su[1] = su[2] = su[3] = 0u; }
#pragma unroll
        for (int t = 0; t < 4; t++) {
            acc[2 * t]     = bf_lo(su[t]);
            acc[2 * t + 1] = bf_hi(su[t]);
        }
    }

    int s[4];
#pragma unroll
    for (int u = 0; u < 4; u++) {
        int idx = u * 4 + g;
        s[u] = (idx < cnt) ? cp[idx] : n;          // n = zero row
    }
    for (int e = 0; e < cnt; e += 16) {
        uint4 v[4];
#pragma unroll
        for (int u = 0; u < 4; u++) v[u] = Hb4[(size_t)s[u] * 16 + c];
        int ns[4];
#pragma unroll
        for (int u = 0; u < 4; u++) {
            int idx = e + 16 + u * 4 + g;
            ns[u] = (idx < cnt) ? cp[idx] : n;
        }
#pragma unroll
        for (int u = 0; u < 4; u++) {
            unsigned int uu[4] = {v[u].x, v[u].y, v[u].z, v[u].w};
#pragma unroll
            for (int t = 0; t < 4; t++) {
                acc[2 * t]     += bf_lo(uu[t]);
                acc[2 * t + 1] += bf_hi(uu[t]);
            }
        }
#pragma unroll
        for (int u = 0; u < 4; u++) s[u] = ns[u];
    }

    // butterfly across the 4 groups (lane bits 4,5)
#pragma unroll
    for (int j = 0; j < 8; j++) {
        acc[j] += __shfl_xor(acc[j], 16);
        acc[j] += __shfl_xor(acc[j], 32);
    }

    float fx = acc[g * 2]     * di;
    float fy = acc[g * 2 + 1] * di;
    Ob[(size_t)i * 64 + c * 4 + g] = pack_bf(fx, fy);
}

// ---------------- launch ----------------

extern "C" void kernel_launch(void* const* d_in, const int* in_sizes, int n_in,
                              void* d_out, int out_size, void* d_ws, size_t ws_size,
                              hipStream_t stream) {
    const float* x  = (const float*)d_in[0];
    const int*   ei = (const int*)d_in[1];     // [2,E] int32
    const float* W1 = (const float*)d_in[2];
    const float* b1 = (const float*)d_in[3];
    const float* W2 = (const float*)d_in[4];
    const float* b2 = (const float*)d_in[5];
    const float* Wa = (const float*)d_in[6];
    const float* ba = (const float*)d_in[7];
    float* out = (float*)d_out;

    int N = in_sizes[0] / D;
    int E = in_sizes[1] / 2;

    int nbuck = (N + 255) >> 8;                       // 196 for N=50000
    int cap = ((E / nbuck) + 2048 + 63) & ~63;

    char* w = (char*)d_ws;
    size_t off = 0;
    auto carve = [&](size_t bytes) -> void* {
        void* p = w + off;
        off = (off + bytes + 255) & ~(size_t)255;
        return p;
    };
    int*   bcur   = (int*)carve(256 * 4);
    float* dinv   = (float*)carve((size_t)(N + 1) * 4);   // +1: dinv[N]=0 sentinel
    int*   rowptr = (int*)carve((size_t)(N + 1) * 4);
    unsigned int* bdata = (unsigned int*)carve((size_t)nbuck * cap * 4);
    int*   csr    = (int*)carve((size_t)E * 4);
    unsigned short* Wf1 = (unsigned short*)carve(16384 * 2);
    unsigned short* WfF = (unsigned short*)carve(16384 * 2);
    float* bpad   = (float*)carve(512);
    unsigned int* HbA = (unsigned int*)carve((size_t)(N + 1) * 64 * 4);  // +1 zero row
    unsigned int* HbB = (unsigned int*)carve((size_t)(N + 1) * 64 * 4);
    (void)ws_size; (void)n_in; (void)out_size;

    int nbNode4 = (N + 3) / 4;
    int nbGemm = (N + 63) / 64;
    int nbP1 = (E + CHUNK - 1) / CHUNK;

    (void)hipMemsetAsync(bcur, 0, 256 * 4, stream);

    // K1: pass1  ||  prep (Wf1, W2@Wa, fused bias, zero-rows, sentinels)
    k_p1_prep<<<nbP1 + 128, 256, 0, stream>>>(ei, E, nbuck, cap, bcur, bdata,
                                              W1, W2, Wa, ba, b2, Wf1, WfF, bpad,
                                              rowptr, dinv,
                                              HbA + (size_t)N * 64, HbB + (size_t)N * 64,
                                              N, nbP1);
    // K2: build (dinv+rowptr+csr)  ||  gemm1 (H1 = bf16(X@W1), unscaled)
    k_build_gemm<<<nbuck + nbGemm, 256, 0, stream>>>(bdata, bcur, cap, dinv, rowptr, csr,
                                                     N, nbuck, x, Wf1, HbA);
    // agg1: h1'_i = bf16( dinv_i * relu( di*(sum dinv_s*H1_s + di*H1_i) + b1 ) )
    agg_gather_kernel<<<nbNode4, 256, 0, stream>>>((const uint4*)HbA, csr, rowptr, dinv, b1, HbB, N);
    // agg2: G_i = bf16( di*(sum h1'_s + h1'_i) )   (prescaled input, r7-exact)
    agg_pre_kernel<<<nbNode4, 256, 0, stream>>>((const uint4*)HbB, csr, rowptr, HbA, N);
    // fused attention: out = softmax( G @ (W2@Wa) + (b2@Wa + ba) )
    k_gemm_final<<<nbGemm, 256, 0, stream>>>(HbA, WfF, bpad, out, N);
}